// Round 1
// baseline (805.995 us; speedup 1.0000x reference)
//
#include <hip/hip_runtime.h>
#include <hip/hip_bf16.h>
#include <math.h>

#define EPSF 1e-5f

typedef __attribute__((ext_vector_type(4))) float f32x4;
typedef __attribute__((ext_vector_type(8))) short s16x8;

// ---------- block reduction (256 threads = 4 waves) ----------
__device__ __forceinline__ float block_reduce_sum_256(float s) {
  #pragma unroll
  for (int o = 32; o > 0; o >>= 1) s += __shfl_xor(s, o, 64);
  __shared__ float red[4];
  int lane = threadIdx.x & 63, wid = threadIdx.x >> 6;
  if (lane == 0) red[wid] = s;
  __syncthreads();
  return red[0] + red[1] + red[2] + red[3];
}

// ---------- K0: h = expmap0(x) as bf16; cx2, 1/(1-cx2) per row ----------
__global__ void k_expmap(const float* __restrict__ x, __hip_bfloat16* __restrict__ h,
                         float* __restrict__ cx2, float* __restrict__ invomc, int K) {
  int row = blockIdx.x;
  const float* xr = x + (size_t)row * K;
  int t = threadIdx.x;
  float v[16];
  float s = 0.f;
  int nit = K >> 8;  // K/256, assumed <=16 (K=4096 -> 16)
  #pragma unroll
  for (int i = 0; i < 16; ++i) {
    if (i < nit) { v[i] = xr[t + (i << 8)]; s += v[i] * v[i]; }
  }
  float nsq = block_reduce_sum_256(s);
  float n = fmaxf(sqrtf(nsq), EPSF);
  float sc = tanhf(n) / n;            // rc = 1
  float hn2 = sc * sc * nsq;          // ||h||^2
  float c2 = fminf(hn2, 1.f - EPSF);
  if (t == 0) { cx2[row] = c2; invomc[row] = 1.f / (1.f - c2); }
  __hip_bfloat16* hr = h + (size_t)row * K;
  #pragma unroll
  for (int i = 0; i < 16; ++i) {
    if (i < nit) hr[t + (i << 8)] = __float2bfloat16(sc * v[i]);
  }
}

// ---------- K1a: partial column sum-of-squares of z (deterministic) ----------
__global__ void k_colsq(const float* __restrict__ z, float* __restrict__ part,
                        int K, int N, int rows_per_chunk) {
  int col = blockIdx.x * 256 + threadIdx.x;
  int r0 = blockIdx.y * rows_per_chunk;
  float s = 0.f;
  for (int r = r0; r < r0 + rows_per_chunk; ++r) {
    float v = z[(size_t)r * N + col];
    s += v * v;
  }
  part[(size_t)blockIdx.y * N + col] = s;
}

// ---------- K1b: finalize per-column scalars ----------
__global__ void k_colfin(const float* __restrict__ part, const float* __restrict__ bias,
                         float* __restrict__ zn2, float* __restrict__ invzn,
                         float* __restrict__ ch, float* __restrict__ sh,
                         int N, int nchunk) {
  int c = blockIdx.x * 256 + threadIdx.x;
  float s = 0.f;
  for (int i = 0; i < nchunk; ++i) s += part[(size_t)i * N + c];
  float zn = fmaxf(sqrtf(s), EPSF);
  zn2[c] = 2.f * zn;
  invzn[c] = 1.f / zn;
  float d = 2.f * bias[c];            // drcr, rc = 1
  ch[c] = coshf(d);
  sh[c] = sinhf(d);
}

// ---------- K1c: z_unit^T (N x K) bf16, LDS tile transpose ----------
__global__ void k_zunitT(const float* __restrict__ z, const float* __restrict__ invzn,
                         __hip_bfloat16* __restrict__ zt, int K, int N) {
  __shared__ float tile[32][33];
  int tx = threadIdx.x, ty = threadIdx.y;   // (32,8)
  int c0 = blockIdx.x * 32, r0 = blockIdx.y * 32;
  float inv = invzn[c0 + tx];
  #pragma unroll
  for (int i = 0; i < 4; ++i)
    tile[ty + i * 8][tx] = z[(size_t)(r0 + ty + i * 8) * N + c0 + tx] * inv;
  __syncthreads();
  #pragma unroll
  for (int i = 0; i < 4; ++i)
    zt[(size_t)(c0 + ty + i * 8) * K + r0 + tx] = __float2bfloat16(tile[tx][ty + i * 8]);
}

// ---------- K2: 128x128 bf16 MFMA GEMM + Poincare-MLR epilogue -> y ----------
__global__ __launch_bounds__(256) void k_gemm_epi(
    const __hip_bfloat16* __restrict__ A,   // h: M x K
    const __hip_bfloat16* __restrict__ Bt,  // z_unit^T: N x K
    const float* __restrict__ cx2, const float* __restrict__ invomc,
    const float* __restrict__ zn2, const float* __restrict__ ch,
    const float* __restrict__ sh,
    float* __restrict__ out, int M, int N, int K) {
  __shared__ __align__(16) char smem[2 * 128 * 32 * 2];  // sA 8KB + sB 8KB
  char* sA = smem;
  char* sB = smem + 128 * 32 * 2;
  int tid = threadIdx.x, lane = tid & 63, wid = tid >> 6;
  int wr = wid >> 1, wc = wid & 1;
  int bm0 = blockIdx.y * 128, bn0 = blockIdx.x * 128;

  f32x4 acc[4][4] = {};

  const __hip_bfloat16* Ab = A + (size_t)bm0 * K;
  const __hip_bfloat16* Bb = Bt + (size_t)bn0 * K;
  int rS = tid >> 2;             // 0..63 (row within 64-row half)
  int kS = (tid & 3) * 8;        // bf16 k-offset within BK=32

  for (int k0 = 0; k0 < K; k0 += 32) {
    #pragma unroll
    for (int i = 0; i < 2; ++i) {
      const void* ga = Ab + (size_t)(i * 64 + rS) * K + k0 + kS;
      const void* gb = Bb + (size_t)(i * 64 + rS) * K + k0 + kS;
      void* la = sA + i * 4096 + wid * 1024;  // + lane*16 implicit
      void* lb = sB + i * 4096 + wid * 1024;
      __builtin_amdgcn_global_load_lds(
          (const __attribute__((address_space(1))) unsigned int*)ga,
          (__attribute__((address_space(3))) unsigned int*)la, 16, 0, 0);
      __builtin_amdgcn_global_load_lds(
          (const __attribute__((address_space(1))) unsigned int*)gb,
          (__attribute__((address_space(3))) unsigned int*)lb, 16, 0, 0);
    }
    __syncthreads();
    s16x8 av[4], bv[4];
    #pragma unroll
    for (int m = 0; m < 4; ++m)
      av[m] = *(const s16x8*)(sA + (wr * 64 + m * 16 + (lane & 15)) * 64 + (lane >> 4) * 16);
    #pragma unroll
    for (int n = 0; n < 4; ++n)
      bv[n] = *(const s16x8*)(sB + (wc * 64 + n * 16 + (lane & 15)) * 64 + (lane >> 4) * 16);
    #pragma unroll
    for (int m = 0; m < 4; ++m)
      #pragma unroll
      for (int n = 0; n < 4; ++n)
        acc[m][n] = __builtin_amdgcn_mfma_f32_16x16x32_bf16(av[m], bv[n], acc[m][n], 0, 0, 0);
    __syncthreads();
  }

  // epilogue: y = sinh( 2*zn * asinh( (2*dot*cosh - (1+cx2)*sinh) / (1-cx2) ) )
  int cr = lane >> 4, cc = lane & 15;
  #pragma unroll
  for (int n = 0; n < 4; ++n) {
    int c = bn0 + wc * 64 + n * 16 + cc;
    float chc = ch[c], shc = sh[c], z2 = zn2[c];
    #pragma unroll
    for (int m = 0; m < 4; ++m) {
      int rbase = bm0 + wr * 64 + m * 16 + cr * 4;
      #pragma unroll
      for (int j = 0; j < 4; ++j) {
        int r = rbase + j;
        float c2 = cx2[r], inv = invomc[r];
        float dot = acc[m][n][j];
        float num = 2.f * dot * chc - (1.f + c2) * shc;
        float mlr = z2 * asinhf(num * inv);
        out[(size_t)r * N + c] = sinhf(mlr);
      }
    }
  }
}

// ---------- K3: ball-lift + logmap0, in place on d_out ----------
__global__ void k_final(float* __restrict__ out, int N) {
  int row = blockIdx.x;
  float* yr = out + (size_t)row * N;
  int t = threadIdx.x;
  float v[16];
  float s = 0.f;
  int nit = N >> 8;
  #pragma unroll
  for (int i = 0; i < 16; ++i) {
    if (i < nit) { v[i] = yr[t + (i << 8)]; s += v[i] * v[i]; }
  }
  float ny2 = block_reduce_sum_256(s);
  float ny = sqrtf(ny2);
  float sfac = 1.f / (1.f + sqrtf(1.f + ny2));  // lift: y_ball = sfac*y
  float w = sfac * ny;                           // ||y_ball||
  float nw = fmaxf(w, EPSF);
  float tt = fminf(nw, 1.f - EPSF);
  float coef = atanhf(tt) * sfac / nw;
  #pragma unroll
  for (int i = 0; i < 16; ++i) {
    if (i < nit) yr[t + (i << 8)] = coef * v[i];
  }
}

extern "C" void kernel_launch(void* const* d_in, const int* in_sizes, int n_in,
                              void* d_out, int out_size, void* d_ws, size_t ws_size,
                              hipStream_t stream) {
  const float* x    = (const float*)d_in[0];
  const float* z    = (const float*)d_in[1];
  const float* bias = (const float*)d_in[2];
  float* out = (float*)d_out;

  int N = in_sizes[2];           // DOUT = 4096
  int K = in_sizes[1] / N;       // DIN  = 4096
  int M = in_sizes[0] / K;       // B    = 8192

  char* ws = (char*)d_ws;
  size_t o = 0;
  __hip_bfloat16* h  = (__hip_bfloat16*)(ws + o); o += (size_t)M * K * 2;
  __hip_bfloat16* zt = (__hip_bfloat16*)(ws + o); o += (size_t)N * K * 2;
  float* cx2    = (float*)(ws + o); o += (size_t)M * 4;
  float* invomc = (float*)(ws + o); o += (size_t)M * 4;
  float* part   = (float*)(ws + o); o += (size_t)32 * N * 4;
  float* zn2    = (float*)(ws + o); o += (size_t)N * 4;
  float* invzn  = (float*)(ws + o); o += (size_t)N * 4;
  float* chb    = (float*)(ws + o); o += (size_t)N * 4;
  float* shb    = (float*)(ws + o); o += (size_t)N * 4;

  const int NCH = 32;
  k_expmap<<<M, 256, 0, stream>>>(x, h, cx2, invomc, K);
  k_colsq<<<dim3(N / 256, NCH), 256, 0, stream>>>(z, part, K, N, K / NCH);
  k_colfin<<<N / 256, 256, 0, stream>>>(part, bias, zn2, invzn, chb, shb, N, NCH);
  k_zunitT<<<dim3(N / 32, K / 32), dim3(32, 8), 0, stream>>>(z, invzn, zt, K, N);
  k_gemm_epi<<<dim3(N / 128, M / 128), 256, 0, stream>>>(h, zt, cx2, invomc, zn2, chb, shb,
                                                         out, M, N, K);
  k_final<<<M, 256, 0, stream>>>(out, N);
}

// Round 2
// 718.601 us; speedup vs baseline: 1.1216x; 1.1216x over previous
//
#include <hip/hip_runtime.h>
#include <hip/hip_bf16.h>
#include <math.h>

#define EPSF 1e-5f

typedef __attribute__((ext_vector_type(4))) float f32x4;
typedef __attribute__((ext_vector_type(8))) short s16x8;

// ---------- block reduction (256 threads = 4 waves) ----------
__device__ __forceinline__ float block_reduce_sum_256(float s) {
  #pragma unroll
  for (int o = 32; o > 0; o >>= 1) s += __shfl_xor(s, o, 64);
  __shared__ float red[4];
  int lane = threadIdx.x & 63, wid = threadIdx.x >> 6;
  if (lane == 0) red[wid] = s;
  __syncthreads();
  return red[0] + red[1] + red[2] + red[3];
}

// ---------- K0: h = expmap0(x) as bf16; cx2, 1/(1-cx2) per row ----------
__global__ void k_expmap(const float* __restrict__ x, __hip_bfloat16* __restrict__ h,
                         float* __restrict__ cx2, float* __restrict__ invomc, int K) {
  int row = blockIdx.x;
  const float* xr = x + (size_t)row * K;
  int t = threadIdx.x;
  float v[16];
  float s = 0.f;
  int nit = K >> 8;
  #pragma unroll
  for (int i = 0; i < 16; ++i) {
    if (i < nit) { v[i] = xr[t + (i << 8)]; s += v[i] * v[i]; }
  }
  float nsq = block_reduce_sum_256(s);
  float n = fmaxf(sqrtf(nsq), EPSF);
  float sc = tanhf(n) / n;            // rc = 1
  float hn2 = sc * sc * nsq;          // ||h||^2
  float c2 = fminf(hn2, 1.f - EPSF);
  if (t == 0) { cx2[row] = c2; invomc[row] = 1.f / (1.f - c2); }
  __hip_bfloat16* hr = h + (size_t)row * K;
  #pragma unroll
  for (int i = 0; i < 16; ++i) {
    if (i < nit) hr[t + (i << 8)] = __float2bfloat16(sc * v[i]);
  }
}

// ---------- K1a: partial column sum-of-squares of z (deterministic) ----------
__global__ void k_colsq(const float* __restrict__ z, float* __restrict__ part,
                        int K, int N, int rows_per_chunk) {
  int col = blockIdx.x * 256 + threadIdx.x;
  int r0 = blockIdx.y * rows_per_chunk;
  float s = 0.f;
  for (int r = r0; r < r0 + rows_per_chunk; ++r) {
    float v = z[(size_t)r * N + col];
    s += v * v;
  }
  part[(size_t)blockIdx.y * N + col] = s;
}

// ---------- K1b: finalize per-column scalars ----------
__global__ void k_colfin(const float* __restrict__ part, const float* __restrict__ bias,
                         float* __restrict__ zn2, float* __restrict__ invzn,
                         float* __restrict__ ch, float* __restrict__ sh,
                         int N, int nchunk) {
  int c = blockIdx.x * 256 + threadIdx.x;
  float s = 0.f;
  for (int i = 0; i < nchunk; ++i) s += part[(size_t)i * N + c];
  float zn = fmaxf(sqrtf(s), EPSF);
  zn2[c] = 2.f * zn;
  invzn[c] = 1.f / zn;
  float d = 2.f * bias[c];
  ch[c] = coshf(d);
  sh[c] = sinhf(d);
}

// ---------- K1c: z_unit^T (N x K) bf16, LDS tile transpose ----------
__global__ void k_zunitT(const float* __restrict__ z, const float* __restrict__ invzn,
                         __hip_bfloat16* __restrict__ zt, int K, int N) {
  __shared__ float tile[32][33];
  int tx = threadIdx.x, ty = threadIdx.y;   // (32,8)
  int c0 = blockIdx.x * 32, r0 = blockIdx.y * 32;
  float inv = invzn[c0 + tx];
  #pragma unroll
  for (int i = 0; i < 4; ++i)
    tile[ty + i * 8][tx] = z[(size_t)(r0 + ty + i * 8) * N + c0 + tx] * inv;
  __syncthreads();
  #pragma unroll
  for (int i = 0; i < 4; ++i)
    zt[(size_t)(c0 + ty + i * 8) * K + r0 + tx] = __float2bfloat16(tile[tx][ty + i * 8]);
}

// ---------- MFMA phase helper (compile-time quadrant) ----------
template<int MQ, int NQ>
__device__ __forceinline__ void mm_phase(f32x4 (&acc)[8][4], const s16x8 (&av)[4][2],
                                         const s16x8 (&bv)[4][2]) {
  #pragma unroll
  for (int i = 0; i < 4; ++i) {
    #pragma unroll
    for (int jn = 0; jn < 2; ++jn) {
      acc[MQ * 4 + i][NQ * 2 + jn] = __builtin_amdgcn_mfma_f32_16x16x32_bf16(
          av[i][0], bv[NQ * 2 + jn][0], acc[MQ * 4 + i][NQ * 2 + jn], 0, 0, 0);
      acc[MQ * 4 + i][NQ * 2 + jn] = __builtin_amdgcn_mfma_f32_16x16x32_bf16(
          av[i][1], bv[NQ * 2 + jn][1], acc[MQ * 4 + i][NQ * 2 + jn], 0, 0, 0);
    }
  }
}

// ---------- K2: 256x256 8-phase bf16 MFMA GEMM + Poincare-MLR epilogue ----------
// LDS layout (per dbuf d, 64KB): A halves at d*65536 + h*16384, B halves at +32768.
// Each 16KB half-tile = [128 rows][64 k] bf16 subtiled [rb=8][cb=2][16][32] with
// st_16x32 swizzle: within-subtile byte ^= (row&8)<<2. global_load_lds writes
// LINEARLY (dest = tid*16 + j*8192); the SOURCE address is inverse-swizzled
// (rule #21), ds_reads apply the same swizzle.
__global__ __launch_bounds__(512, 2) void k_gemm_epi(
    const __hip_bfloat16* __restrict__ A,   // h: M x K
    const __hip_bfloat16* __restrict__ Bt,  // z_unit^T: N x K
    const float* __restrict__ cx2, const float* __restrict__ invomc,
    const float* __restrict__ zn2, const float* __restrict__ ch,
    const float* __restrict__ sh,
    float* __restrict__ out, int M, int N, int K) {
  __shared__ __align__(16) char smem[131072];
  const int K2 = K * 2;
  int tid = threadIdx.x, lane = tid & 63, wid = tid >> 6;
  int wm = wid >> 2, wn = wid & 3;

  // bijective XCD swizzle (gridDim.x % 8 == 0 here: 512 blocks)
  int bid = blockIdx.x;
  int cpx = gridDim.x >> 3;
  int swz = (bid & 7) * cpx + (bid >> 3);
  int nbx = N >> 8;
  int bx = swz % nbx, by = swz / nbx;
  int bm0 = by * 256, bn0 = bx * 256;

  // ---- staging per-thread constants (inverse-swizzled global source) ----
  int rr = (tid >> 2) & 15;
  int cbyte = ((tid & 3) * 16) ^ ((rr & 8) << 2);
  int kb = ((tid >> 6) & 1) * 64 + cbyte;        // k-byte within tile [0,128)
  int r0 = ((tid >> 7) << 4) + rr;               // row for j=0; j=1 adds 64
  size_t pOff0 = (size_t)r0 * K2 + kb;
  size_t pOff1 = (size_t)(r0 + 64) * K2 + kb;
  int ldsW = wid * 1024;                          // linear dest slot (lane*16 implicit)

  const char* aPan0 = (const char*)A + (size_t)bm0 * K2;
  const char* aPan1 = aPan0 + (size_t)128 * K2;
  const char* bPan0 = (const char*)Bt + (size_t)bn0 * K2;
  const char* bPan1 = bPan0 + (size_t)128 * K2;

  // stage one half-tile (2 x global_load_lds, 16B/lane, linear LDS dest)
  auto STAGE = [&](const char* pan, int ldsBase, int ktOff) {
    __builtin_amdgcn_global_load_lds(
        (const __attribute__((address_space(1))) unsigned int*)(pan + ktOff + pOff0),
        (__attribute__((address_space(3))) unsigned int*)(smem + ldsBase + ldsW), 16, 0, 0);
    __builtin_amdgcn_global_load_lds(
        (const __attribute__((address_space(1))) unsigned int*)(pan + ktOff + pOff1),
        (__attribute__((address_space(3))) unsigned int*)(smem + ldsBase + ldsW + 8192), 16, 0, 0);
  };

  // ---- LDS read base (swizzled) ----
  int labase = (lane & 15) * 64 + (((lane >> 4) * 16) ^ ((lane & 8) << 2));

  s16x8 av[4][2], bv[4][2];
  f32x4 acc[8][4] = {};

  auto RDA = [&](int d, int mq) {
    const char* p = smem + d * 65536 + wm * 16384 + mq * 8192 + labase;
    #pragma unroll
    for (int i = 0; i < 4; ++i) {
      av[i][0] = *(const s16x8*)(p + i * 2048);
      av[i][1] = *(const s16x8*)(p + i * 2048 + 1024);
    }
  };
  auto RDB = [&](int d) {
    const char* p = smem + d * 65536 + 32768 + (wn >> 1) * 16384 + (wn & 1) * 8192 + labase;
    #pragma unroll
    for (int f = 0; f < 4; ++f) {
      bv[f][0] = *(const s16x8*)(p + f * 2048);
      bv[f][1] = *(const s16x8*)(p + f * 2048 + 1024);
    }
  };

  int NT = K >> 6;   // K-tiles of 64

  // ---- prologue: tile0 (all 4 halves) + tile1 (B0,B1,A0) = 14 loads ----
  STAGE(bPan0, 32768, 0);  STAGE(bPan1, 49152, 0);
  STAGE(aPan0, 0, 0);      STAGE(aPan1, 16384, 0);
  if (NT > 1) {
    STAGE(bPan0, 65536 + 32768, 128);  STAGE(bPan1, 65536 + 49152, 128);
    STAGE(aPan0, 65536, 128);
  }
  asm volatile("s_waitcnt vmcnt(6)" ::: "memory");
  __builtin_amdgcn_s_barrier();

  for (int kt = 0; kt < NT; ++kt) {
    int d = kt & 1;
    int dn = d ^ 1;
    int kOff1 = (kt + 1) << 7;
    int kOff2 = (kt + 2) << 7;
    // ---- phase 0: (mq0, nq0); stage (kt+1, A1) -> buf dn ----
    RDA(d, 0); RDB(d);
    if (kt + 1 < NT) STAGE(aPan1, dn * 65536 + 16384, kOff1);
    __builtin_amdgcn_s_barrier();
    asm volatile("s_waitcnt lgkmcnt(0)" ::: "memory");
    __builtin_amdgcn_s_setprio(1);
    mm_phase<0, 0>(acc, av, bv);
    __builtin_amdgcn_s_setprio(0);
    __builtin_amdgcn_s_barrier();
    // ---- phase 1: (mq0, nq1); stage (kt+2, B0) -> buf d (B-region free after p0) ----
    if (kt + 2 < NT) STAGE(bPan0, d * 65536 + 32768, kOff2);
    __builtin_amdgcn_s_barrier();
    __builtin_amdgcn_s_setprio(1);
    mm_phase<0, 1>(acc, av, bv);
    __builtin_amdgcn_s_setprio(0);
    __builtin_amdgcn_s_barrier();
    // ---- phase 2: (mq1, nq0); read A-mq1; stage (kt+2, B1) ----
    RDA(d, 1);
    if (kt + 2 < NT) STAGE(bPan1, d * 65536 + 49152, kOff2);
    __builtin_amdgcn_s_barrier();
    asm volatile("s_waitcnt lgkmcnt(0)" ::: "memory");
    __builtin_amdgcn_s_setprio(1);
    mm_phase<1, 0>(acc, av, bv);
    __builtin_amdgcn_s_setprio(0);
    __builtin_amdgcn_s_barrier();
    // ---- phase 3: (mq1, nq1); stage (kt+2, A0) (A0-region free after p1) ----
    if (kt + 2 < NT) STAGE(aPan0, d * 65536, kOff2);
    __builtin_amdgcn_s_barrier();
    __builtin_amdgcn_s_setprio(1);
    mm_phase<1, 1>(acc, av, bv);
    __builtin_amdgcn_s_setprio(0);
    if (kt + 2 < NT) { asm volatile("s_waitcnt vmcnt(6)" ::: "memory"); }
    else            { asm volatile("s_waitcnt vmcnt(0)" ::: "memory"); }
    __builtin_amdgcn_s_barrier();
  }

  // ---- epilogue: y = sinh( 2*zn * asinh( (2*dot*ch - (1+cx2)*sh) / (1-cx2) ) ) ----
  int cr = lane >> 4, cc = lane & 15;
  #pragma unroll
  for (int fn = 0; fn < 4; ++fn) {
    int c = bn0 + wn * 64 + fn * 16 + cc;
    float chc = ch[c], shc = sh[c], z2 = zn2[c];
    #pragma unroll
    for (int fm = 0; fm < 8; ++fm) {
      int rb = bm0 + wm * 128 + fm * 16 + cr * 4;
      #pragma unroll
      for (int j = 0; j < 4; ++j) {
        int r = rb + j;
        float c2 = cx2[r], inv = invomc[r];
        float dot = acc[fm][fn][j];
        float num = 2.f * dot * chc - (1.f + c2) * shc;
        float mlr = z2 * asinhf(num * inv);
        out[(size_t)r * N + c] = sinhf(mlr);
      }
    }
  }
}

// ---------- K3: ball-lift + logmap0, in place on d_out ----------
__global__ void k_final(float* __restrict__ out, int N) {
  int row = blockIdx.x;
  float* yr = out + (size_t)row * N;
  int t = threadIdx.x;
  float v[16];
  float s = 0.f;
  int nit = N >> 8;
  #pragma unroll
  for (int i = 0; i < 16; ++i) {
    if (i < nit) { v[i] = yr[t + (i << 8)]; s += v[i] * v[i]; }
  }
  float ny2 = block_reduce_sum_256(s);
  float ny = sqrtf(ny2);
  float sfac = 1.f / (1.f + sqrtf(1.f + ny2));
  float w = sfac * ny;
  float nw = fmaxf(w, EPSF);
  float tt = fminf(nw, 1.f - EPSF);
  float coef = atanhf(tt) * sfac / nw;
  #pragma unroll
  for (int i = 0; i < 16; ++i) {
    if (i < nit) yr[t + (i << 8)] = coef * v[i];
  }
}

extern "C" void kernel_launch(void* const* d_in, const int* in_sizes, int n_in,
                              void* d_out, int out_size, void* d_ws, size_t ws_size,
                              hipStream_t stream) {
  const float* x    = (const float*)d_in[0];
  const float* z    = (const float*)d_in[1];
  const float* bias = (const float*)d_in[2];
  float* out = (float*)d_out;

  int N = in_sizes[2];           // DOUT = 4096
  int K = in_sizes[1] / N;       // DIN  = 4096
  int M = in_sizes[0] / K;       // B    = 8192

  char* ws = (char*)d_ws;
  size_t o = 0;
  __hip_bfloat16* h  = (__hip_bfloat16*)(ws + o); o += (size_t)M * K * 2;
  __hip_bfloat16* zt = (__hip_bfloat16*)(ws + o); o += (size_t)N * K * 2;
  float* cx2    = (float*)(ws + o); o += (size_t)M * 4;
  float* invomc = (float*)(ws + o); o += (size_t)M * 4;
  float* part   = (float*)(ws + o); o += (size_t)32 * N * 4;
  float* zn2    = (float*)(ws + o); o += (size_t)N * 4;
  float* invzn  = (float*)(ws + o); o += (size_t)N * 4;
  float* chb    = (float*)(ws + o); o += (size_t)N * 4;
  float* shb    = (float*)(ws + o); o += (size_t)N * 4;

  const int NCH = 32;
  k_expmap<<<M, 256, 0, stream>>>(x, h, cx2, invomc, K);
  k_colsq<<<dim3(N / 256, NCH), 256, 0, stream>>>(z, part, K, N, K / NCH);
  k_colfin<<<N / 256, 256, 0, stream>>>(part, bias, zn2, invzn, chb, shb, N, NCH);
  k_zunitT<<<dim3(N / 32, K / 32), dim3(32, 8), 0, stream>>>(z, invzn, zt, K, N);
  int grid = (M / 256) * (N / 256);
  k_gemm_epi<<<grid, 512, 0, stream>>>(h, zt, cx2, invomc, zn2, chb, shb, out, M, N, K);
  k_final<<<M, 256, 0, stream>>>(out, N);
}